// Round 7
// baseline (285.467 us; speedup 1.0000x reference)
//
#include <hip/hip_runtime.h>
#include <hip/hip_bf16.h>
#include <math.h>

#define D_MODEL 1024
#define NHEADS  16
#define HDIM    64
#define BATCH   4
#define SEQ     2048

typedef __attribute__((ext_vector_type(8))) short short8;
typedef __attribute__((ext_vector_type(4))) float f32x4;

__device__ __forceinline__ short bf16_of(float f) {
  __hip_bfloat16 h = __float2bfloat16(f);
  return *reinterpret_cast<short*>(&h);
}

__device__ __forceinline__ unsigned pack2(float lo, float hi) {
  return (unsigned)(unsigned short)bf16_of(lo) |
         ((unsigned)(unsigned short)bf16_of(hi) << 16);
}

__device__ __forceinline__ short8 mk_frag(unsigned a, unsigned b, unsigned c, unsigned d) {
  union { unsigned u[4]; short8 s; } t;
  t.u[0] = a; t.u[1] = b; t.u[2] = c; t.u[3] = d;
  return t.s;
}

__device__ __forceinline__ float fast_exp2(float x) {
  float r;
  asm("v_exp_f32 %0, %1" : "=v"(r) : "v"(x));
  return r;
}

// async global->LDS DMA, 16B per lane; lds dest = wave-uniform base + lane*16
__device__ __forceinline__ void gload16(const void* g, void* l) {
  __builtin_amdgcn_global_load_lds((const __attribute__((address_space(1))) void*)g,
                                   (__attribute__((address_space(3))) void*)l, 16, 0, 0);
}

// ---------------- fp32 -> bf16 convert: all 4 weights in one launch ----------------
__global__ __launch_bounds__(256) void cvt4(const float* __restrict__ s0,
                                            const float* __restrict__ s1,
                                            const float* __restrict__ s2,
                                            const float* __restrict__ s3,
                                            short* __restrict__ dst) {
  const int w = blockIdx.y;
  const float* s = (w == 0) ? s0 : (w == 1) ? s1 : (w == 2) ? s2 : s3;
  short* d = dst + (size_t)w * D_MODEL * D_MODEL;
  const int n4 = D_MODEL * D_MODEL / 4;
  int stride = gridDim.x * blockDim.x;
  for (int i = blockIdx.x * blockDim.x + threadIdx.x; i < n4; i += stride) {
    float4 v = reinterpret_cast<const float4*>(s)[i];
    reinterpret_cast<uint2*>(d)[i] = make_uint2(pack2(v.x, v.y), pack2(v.z, v.w));
  }
}

// ---------------- fused QKV projection GEMM ----------------
// grid (24, 64). XCD-grouping remap (T1): all 24 bx-tiles of a given by land on
// one XCD so the shared A-row-tile stays in that XCD's L2 (FETCH = compulsory).
// T14 register prefetch: tile k+1's global loads are issued BEFORE tile k's
// MFMAs; cvt+LDS-write happen after the post-MFMA barrier, so global latency
// is hidden under frag reads + 16 MFMAs + barrier instead of being serial.
__global__ __launch_bounds__(256) void qkv_gemm(
    const float* __restrict__ qa, const float* __restrict__ ka, const float* __restrict__ va,
    const short* __restrict__ Wqkv,
    const float* __restrict__ bq, const float* __restrict__ bk, const float* __restrict__ bv,
    short* __restrict__ Qb, short* __restrict__ Kb, short* __restrict__ Vb)
{
  const int tid  = threadIdx.x;
  const int lane = tid & 63;
  const int wave = tid >> 6;
  // bijective remap: linear L -> (xcd = L&7, slot = L>>3); by ≡ xcd (mod 8)
  const int Lb  = blockIdx.x + 24 * blockIdx.y;
  const int xcd = Lb & 7;
  const int sl  = Lb >> 3;              // 0..191
  const int bx  = sl % 24;
  const int by  = (sl / 24) * 8 + xcd;  // 0..63

  const int sel = bx >> 3;
  const float* A    = (sel == 0) ? qa : (sel == 1) ? ka : va;
  const float* bias = (sel == 0) ? bq : (sel == 1) ? bk : bv;
  short* Out        = (sel == 0) ? Qb : (sel == 1) ? Kb : Vb;
  const int m0  = by * 128;
  const int n0g = bx * 128;          // row into Wqkv (0..3071)
  const int n0  = n0g & 1023;        // col into output tensor
  const int wm = (wave >> 1) * 64;
  const int wn = (wave & 1) * 64;

  __shared__ short As[128][40];
  __shared__ short Bs[128][40];

  f32x4 acc[4][4];
#pragma unroll
  for (int m = 0; m < 4; ++m)
#pragma unroll
    for (int n = 0; n < 4; ++n)
      acc[m][n] = (f32x4){0.f, 0.f, 0.f, 0.f};

  // per-thread staging coordinates
  const int arow = tid >> 3, ac4 = (tid & 7) * 4;       // A: 4 chunks, stride 32 rows
  const int brow = tid >> 2, bc8 = (tid & 3) * 8;       // B: 2 chunks, stride 64 rows
  const float* Ap = &A[(size_t)(m0 + arow) * D_MODEL + ac4];
  const short* Bp = &Wqkv[(size_t)(n0g + brow) * D_MODEL + bc8];

  float4 av[4];
  uint4  bv4[2];

  // prologue: load tile 0 into regs, cvt+write to LDS
#pragma unroll
  for (int i = 0; i < 4; ++i)
    av[i] = *reinterpret_cast<const float4*>(Ap + (size_t)(i * 32) * D_MODEL);
#pragma unroll
  for (int i = 0; i < 2; ++i)
    bv4[i] = *reinterpret_cast<const uint4*>(Bp + (size_t)(i * 64) * D_MODEL);
#pragma unroll
  for (int i = 0; i < 4; ++i)
    *reinterpret_cast<uint2*>(&As[arow + i * 32][ac4]) =
        make_uint2(pack2(av[i].x, av[i].y), pack2(av[i].z, av[i].w));
#pragma unroll
  for (int i = 0; i < 2; ++i)
    *reinterpret_cast<uint4*>(&Bs[brow + i * 64][bc8]) = bv4[i];
  __syncthreads();

  for (int k0 = 0; k0 < D_MODEL; k0 += 32) {
    const bool more = (k0 + 32) < D_MODEL;
    // issue next tile's loads NOW (consumed after MFMA + barrier)
    if (more) {
#pragma unroll
      for (int i = 0; i < 4; ++i)
        av[i] = *reinterpret_cast<const float4*>(Ap + (size_t)(i * 32) * D_MODEL + (k0 + 32));
#pragma unroll
      for (int i = 0; i < 2; ++i)
        bv4[i] = *reinterpret_cast<const uint4*>(Bp + (size_t)(i * 64) * D_MODEL + (k0 + 32));
    }

    short8 afr[4], bfr[4];
#pragma unroll
    for (int m = 0; m < 4; ++m)
      afr[m] = *reinterpret_cast<const short8*>(&As[wm + m * 16 + (lane & 15)][(lane >> 4) * 8]);
#pragma unroll
    for (int n = 0; n < 4; ++n)
      bfr[n] = *reinterpret_cast<const short8*>(&Bs[wn + n * 16 + (lane & 15)][(lane >> 4) * 8]);
    __builtin_amdgcn_s_setprio(1);
#pragma unroll
    for (int m = 0; m < 4; ++m)
#pragma unroll
      for (int n = 0; n < 4; ++n)
        acc[m][n] = __builtin_amdgcn_mfma_f32_16x16x32_bf16(afr[m], bfr[n], acc[m][n], 0, 0, 0);
    __builtin_amdgcn_s_setprio(0);
    __syncthreads();            // all waves done reading LDS for this step

    if (more) {
#pragma unroll
      for (int i = 0; i < 4; ++i)
        *reinterpret_cast<uint2*>(&As[arow + i * 32][ac4]) =
            make_uint2(pack2(av[i].x, av[i].y), pack2(av[i].z, av[i].w));
#pragma unroll
      for (int i = 0; i < 2; ++i)
        *reinterpret_cast<uint4*>(&Bs[brow + i * 64][bc8]) = bv4[i];
      __syncthreads();          // staged tile visible before next ds_read
    }
  }

#pragma unroll
  for (int n = 0; n < 4; ++n) {
    int col = n0 + wn + n * 16 + (lane & 15);
    float bval = bias[col];
#pragma unroll
    for (int m = 0; m < 4; ++m) {
      int rowb = m0 + wm + m * 16 + (lane >> 4) * 4;
#pragma unroll
      for (int r = 0; r < 4; ++r)
        Out[(size_t)(rowb + r) * D_MODEL + col] = bf16_of(acc[m][n][r] + bval);
    }
  }
}

// ---------------- output GEMM: Out[M,N] = A[M,K] @ Bw[N,K]^T + bias (bf16 A, f32 out) ----------------
// Both operands via global_load_lds DMA; XCD-grouping remap like qkv_gemm.
__global__ __launch_bounds__(256) void gemm_out(
    const short* __restrict__ A, const short* __restrict__ Bw,
    const float* __restrict__ bias, float* __restrict__ Out,
    int M, int N, int K)
{
  const int tid  = threadIdx.x;
  const int lane = tid & 63;
  const int wave = tid >> 6;
  const int Lb  = blockIdx.x + 8 * blockIdx.y;
  const int xcd = Lb & 7;
  const int sl  = Lb >> 3;             // 0..63
  const int bx  = sl & 7;
  const int by  = (sl >> 3) * 8 + xcd; // 0..63
  const int m0 = by * 128;
  const int n0 = bx * 128;
  const int wm = (wave >> 1) * 64;
  const int wn = (wave & 1) * 64;

  __shared__ short As[128 * 32];
  __shared__ short Bs[128 * 32];

  f32x4 acc[4][4];
#pragma unroll
  for (int m = 0; m < 4; ++m)
#pragma unroll
    for (int n = 0; n < 4; ++n)
      acc[m][n] = (f32x4){0.f, 0.f, 0.f, 0.f};

  for (int k0 = 0; k0 < K; k0 += 32) {
#pragma unroll
    for (int i = 0; i < 2; ++i) {
      int t = i * 256 + wave * 64 + lane;
      int row = t >> 2, c8 = (t & 3) * 8;
      gload16(&A[(size_t)(m0 + row) * K + k0 + c8],  &As[i * 2048 + wave * 512]);
      gload16(&Bw[(size_t)(n0 + row) * K + k0 + c8], &Bs[i * 2048 + wave * 512]);
    }
    __syncthreads();

    short8 afr[4], bfr[4];
#pragma unroll
    for (int m = 0; m < 4; ++m)
      afr[m] = *reinterpret_cast<const short8*>(&As[(wm + m * 16 + (lane & 15)) * 32 + (lane >> 4) * 8]);
#pragma unroll
    for (int n = 0; n < 4; ++n)
      bfr[n] = *reinterpret_cast<const short8*>(&Bs[(wn + n * 16 + (lane & 15)) * 32 + (lane >> 4) * 8]);
#pragma unroll
    for (int m = 0; m < 4; ++m)
#pragma unroll
      for (int n = 0; n < 4; ++n)
        acc[m][n] = __builtin_amdgcn_mfma_f32_16x16x32_bf16(afr[m], bfr[n], acc[m][n], 0, 0, 0);
    __syncthreads();
  }

#pragma unroll
  for (int n = 0; n < 4; ++n) {
    int col = n0 + wn + n * 16 + (lane & 15);
    float bval = bias[col];
#pragma unroll
    for (int m = 0; m < 4; ++m) {
      int rowb = m0 + wm + m * 16 + (lane >> 4) * 4;
#pragma unroll
      for (int r = 0; r < 4; ++r)
        Out[(size_t)(rowb + r) * N + col] = acc[m][n][r] + bval;
    }
  }
}

// ---------------- per-head V transpose: V[B,S,D] -> VT[B,H,HDIM,SEQ] ----------------
__global__ __launch_bounds__(256) void transpose_v(const short* __restrict__ V,
                                                   short* __restrict__ VT) {
  int st = blockIdx.x;
  int bh = blockIdx.y;
  int b = bh >> 4, h = bh & 15;
  __shared__ short T[64][72];
  int tid = threadIdx.x;
#pragma unroll
  for (int i = 0; i < 2; ++i) {
    int c = tid + i * 256;
    int srow = c >> 3;
    int d8 = (c & 7) * 8;
    *reinterpret_cast<uint4*>(&T[srow][d8]) = *reinterpret_cast<const uint4*>(
        &V[((size_t)b * SEQ + st * 64 + srow) * D_MODEL + h * HDIM + d8]);
  }
  __syncthreads();
#pragma unroll
  for (int i = 0; i < 2; ++i) {
    int c = tid + i * 256;
    int drow = c >> 3;
    int s8 = (c & 7) * 8;
    __align__(16) short tmp[8];
#pragma unroll
    for (int j = 0; j < 8; ++j) tmp[j] = T[s8 + j][drow];
    *reinterpret_cast<uint4*>(
        &VT[(((size_t)b * NHEADS + h) * HDIM + drow) * SEQ + st * 64 + s8]) =
        *reinterpret_cast<uint4*>(tmp);
  }
}

// ---------------- flash attention, swapped-QK^T, fixed-shift softmax ----------------
// grid: (SEQ/128, B*H), 512 thr = 8 waves; each wave owns 16 query rows.
// Lane holds S^T[key][q], q=lane&15. Fixed softmax shift (10 nats) removes all
// max tracking; denominator accumulated via ones-MFMA (o_l). P lane-local for
// PV via key-permutation pi; V^T staged permuted.
__global__ __launch_bounds__(512) void attn_fwd(
    const short* __restrict__ Q,   // [B,S,D] bf16
    const short* __restrict__ Kg,  // [B,S,D] bf16
    const short* __restrict__ VT,  // [B,H,HDIM,SEQ] bf16
    short* __restrict__ Oc)        // [B,S,D] bf16 (concat)
{
  const int tid = threadIdx.x, lane = tid & 63, wave = tid >> 6;
  const int qi = lane & 15, g = lane >> 4;
  const int q0 = blockIdx.x * 128;
  const int bh = blockIdx.y, b = bh >> 4, h = bh & 15;

  __shared__ short Ks[2][64][72];   // [buf][key][d]
  __shared__ short Vs[2][64][72];   // [buf][d][pi(key)]

  const float CEXP = 0.18033688f;   // log2(e)/8
  const float SMC  = 14.4269504f;   // 80 * CEXP  (fixed 10-nat shift)
  const short8 ones = mk_frag(0x3F803F80u, 0x3F803F80u, 0x3F803F80u, 0x3F803F80u);

  short8 qfr[2];
  {
    int qrow = q0 + wave * 16 + qi;
    const short* qp = &Q[((size_t)b * SEQ + qrow) * D_MODEL + h * HDIM + g * 8];
    qfr[0] = *reinterpret_cast<const short8*>(qp);
    qfr[1] = *reinterpret_cast<const short8*>(qp + 32);
  }

  const size_t kbase = ((size_t)b * SEQ) * D_MODEL + h * HDIM;
  const size_t vbase = ((size_t)bh * HDIM) * SEQ;

  f32x4 o[4], o_l;
#pragma unroll
  for (int db = 0; db < 4; ++db) o[db] = (f32x4){0.f, 0.f, 0.f, 0.f};
  o_l = (f32x4){0.f, 0.f, 0.f, 0.f};

  // prologue: stage tile 0 into buffer 0 (1 K-chunk + 1 V-chunk per thread)
  {
    int row = tid >> 3, sub = tid & 7;
    *reinterpret_cast<uint4*>(&Ks[0][row][sub * 8]) =
        *reinterpret_cast<const uint4*>(&Kg[kbase + (size_t)row * D_MODEL + sub * 8]);
    uint4 vv = *reinterpret_cast<const uint4*>(&VT[vbase + (size_t)row * SEQ + sub * 8]);
    int posA = 32 * (sub >> 2) + 16 * (sub & 1) + 4 * ((sub >> 1) & 1);
    *reinterpret_cast<uint2*>(&Vs[0][row][posA])     = make_uint2(vv.x, vv.y);
    *reinterpret_cast<uint2*>(&Vs[0][row][posA + 8]) = make_uint2(vv.z, vv.w);
  }
  __syncthreads();

  for (int t = 0; t < SEQ / 64; ++t) {
    const int cur = t & 1;
    const bool more = (t + 1) < SEQ / 64;
    const int row = tid >> 3, sub = tid & 7;
    uint4 kreg, vreg;
    if (more) {
      int k0 = (t + 1) * 64;
      kreg = *reinterpret_cast<const uint4*>(&Kg[kbase + (size_t)(k0 + row) * D_MODEL + sub * 8]);
      vreg = *reinterpret_cast<const uint4*>(&VT[vbase + (size_t)row * SEQ + k0 + sub * 8]);
    }

    // QK^T swapped: A=K (row=key), B=Q (col=q)
    f32x4 st[4];
    __builtin_amdgcn_s_setprio(1);
#pragma unroll
    for (int n = 0; n < 4; ++n) {
      short8 a0 = *reinterpret_cast<const short8*>(&Ks[cur][n * 16 + qi][g * 8]);
      short8 a1 = *reinterpret_cast<const short8*>(&Ks[cur][n * 16 + qi][32 + g * 8]);
      f32x4 z = (f32x4){0.f, 0.f, 0.f, 0.f};
      z = __builtin_amdgcn_mfma_f32_16x16x32_bf16(a0, qfr[0], z, 0, 0, 0);
      z = __builtin_amdgcn_mfma_f32_16x16x32_bf16(a1, qfr[1], z, 0, 0, 0);
      st[n] = z;
    }
    __builtin_amdgcn_s_setprio(0);

    // fixed-shift softmax: p = 2^(s*CEXP - SMC); no max, no cross-lane
    unsigned pk[4][2];
#pragma unroll
    for (int n = 0; n < 4; ++n) {
#pragma unroll
      for (int r = 0; r < 4; ++r)
        st[n][r] = fast_exp2(fmaf(st[n][r], CEXP, -SMC));
      pk[n][0] = pack2(st[n][0], st[n][1]);
      pk[n][1] = pack2(st[n][2], st[n][3]);
    }

    // stage next tile into the other buffer (loads already in flight)
    if (more) {
      const int nb = cur ^ 1;
      *reinterpret_cast<uint4*>(&Ks[nb][row][sub * 8]) = kreg;
      int posA = 32 * (sub >> 2) + 16 * (sub & 1) + 4 * ((sub >> 1) & 1);
      *reinterpret_cast<uint2*>(&Vs[nb][row][posA])     = make_uint2(vreg.x, vreg.y);
      *reinterpret_cast<uint2*>(&Vs[nb][row][posA + 8]) = make_uint2(vreg.z, vreg.w);
    }

    // PV: O^T[d][q] += V^T[d][pi(k)] * P^T[pi(k)][q]; l via ones-MFMA
    short8 pb0 = mk_frag(pk[0][0], pk[0][1], pk[1][0], pk[1][1]);
    short8 pb1 = mk_frag(pk[2][0], pk[2][1], pk[3][0], pk[3][1]);
    __builtin_amdgcn_s_setprio(1);
#pragma unroll
    for (int db = 0; db < 4; ++db) {
      short8 va0 = *reinterpret_cast<const short8*>(&Vs[cur][db * 16 + qi][g * 8]);
      short8 va1 = *reinterpret_cast<const short8*>(&Vs[cur][db * 16 + qi][32 + g * 8]);
      o[db] = __builtin_amdgcn_mfma_f32_16x16x32_bf16(va0, pb0, o[db], 0, 0, 0);
      o[db] = __builtin_amdgcn_mfma_f32_16x16x32_bf16(va1, pb1, o[db], 0, 0, 0);
    }
    o_l = __builtin_amdgcn_mfma_f32_16x16x32_bf16(ones, pb0, o_l, 0, 0, 0);
    o_l = __builtin_amdgcn_mfma_f32_16x16x32_bf16(ones, pb1, o_l, 0, 0, 0);
    __builtin_amdgcn_s_setprio(0);

    __syncthreads();
  }

  // epilogue: transpose O^T -> rows via dead K buffer, then coalesced store
  short (*Os)[72] = reinterpret_cast<short(*)[72]>(&Ks[0][0][0]);  // [128][72]
  float inv = 1.f / o_l[0];
#pragma unroll
  for (int db = 0; db < 4; ++db)
#pragma unroll
    for (int r = 0; r < 4; ++r)
      Os[wave * 16 + qi][db * 16 + g * 4 + r] = bf16_of(o[db][r] * inv);
  __syncthreads();
#pragma unroll
  for (int i = 0; i < 2; ++i) {
    int c = tid + i * 512;
    int row = c >> 3, sub = c & 7;
    *reinterpret_cast<uint4*>(&Oc[((size_t)b * SEQ + q0 + row) * D_MODEL + h * HDIM + sub * 8]) =
        *reinterpret_cast<const uint4*>(&Os[row][sub * 8]);
  }
}

// ---------------- launch ----------------
extern "C" void kernel_launch(void* const* d_in, const int* in_sizes, int n_in,
                              void* d_out, int out_size, void* d_ws, size_t ws_size,
                              hipStream_t stream)
{
  const float* q  = (const float*)d_in[0];
  const float* k  = (const float*)d_in[1];
  const float* v  = (const float*)d_in[2];
  const float* Wq = (const float*)d_in[3];
  const float* bq = (const float*)d_in[4];
  const float* Wk = (const float*)d_in[5];
  const float* bk = (const float*)d_in[6];
  const float* Wv = (const float*)d_in[7];
  const float* bv = (const float*)d_in[8];
  const float* Wo = (const float*)d_in[9];
  const float* bo = (const float*)d_in[10];

  char* ws = (char*)d_ws;
  const size_t MB = 1ull << 20;
  short* Wqkv_b = (short*)(ws + 0 * MB);   // [3072][1024] bf16 (q,k,v contiguous)
  short* Wo_b   = (short*)(ws + 6 * MB);
  short* Qb     = (short*)(ws + 8 * MB);
  short* Kb     = (short*)(ws + 24 * MB);
  short* Vb     = (short*)(ws + 40 * MB);
  short* VTb    = (short*)(ws + 56 * MB);
  short* Ac     = (short*)(ws + 40 * MB);  // aliases Vb (dead after transpose)

  const int M = BATCH * SEQ;

  cvt4<<<dim3(256, 4), 256, 0, stream>>>(Wq, Wk, Wv, Wo, Wqkv_b);

  qkv_gemm<<<dim3(24, M / 128), 256, 0, stream>>>(q, k, v, Wqkv_b, bq, bk, bv, Qb, Kb, Vb);

  transpose_v<<<dim3(SEQ / 64, BATCH * NHEADS), 256, 0, stream>>>(Vb, VTb);

  attn_fwd<<<dim3(SEQ / 128, BATCH * NHEADS), 512, 0, stream>>>(Qb, Kb, VTb, Ac);

  gemm_out<<<dim3(D_MODEL / 128, M / 128), 256, 0, stream>>>(Ac, Wo_b, bo, (float*)d_out,
                                                             M, D_MODEL, D_MODEL);
}

// Round 8
// 221.135 us; speedup vs baseline: 1.2909x; 1.2909x over previous
//
#include <hip/hip_runtime.h>
#include <hip/hip_bf16.h>
#include <math.h>

#define D_MODEL 1024
#define NHEADS  16
#define HDIM    64
#define BATCH   4
#define SEQ     2048

typedef __attribute__((ext_vector_type(8))) short short8;
typedef __attribute__((ext_vector_type(4))) float f32x4;

__device__ __forceinline__ short bf16_of(float f) {
  __hip_bfloat16 h = __float2bfloat16(f);
  return *reinterpret_cast<short*>(&h);
}

__device__ __forceinline__ unsigned pack2(float lo, float hi) {
  return (unsigned)(unsigned short)bf16_of(lo) |
         ((unsigned)(unsigned short)bf16_of(hi) << 16);
}

__device__ __forceinline__ short8 mk_frag(unsigned a, unsigned b, unsigned c, unsigned d) {
  union { unsigned u[4]; short8 s; } t;
  t.u[0] = a; t.u[1] = b; t.u[2] = c; t.u[3] = d;
  return t.s;
}

__device__ __forceinline__ float fast_exp2(float x) {
  float r;
  asm("v_exp_f32 %0, %1" : "=v"(r) : "v"(x));
  return r;
}

// async global->LDS DMA, 16B per lane; lds dest = wave-uniform base + lane*16
__device__ __forceinline__ void gload16(const void* g, void* l) {
  __builtin_amdgcn_global_load_lds((const __attribute__((address_space(1))) void*)g,
                                   (__attribute__((address_space(3))) void*)l, 16, 0, 0);
}

// ---------------- fp32 -> bf16 convert: all 4 weights in one launch ----------------
__global__ __launch_bounds__(256) void cvt4(const float* __restrict__ s0,
                                            const float* __restrict__ s1,
                                            const float* __restrict__ s2,
                                            const float* __restrict__ s3,
                                            short* __restrict__ dst) {
  const int w = blockIdx.y;
  const float* s = (w == 0) ? s0 : (w == 1) ? s1 : (w == 2) ? s2 : s3;
  short* d = dst + (size_t)w * D_MODEL * D_MODEL;
  const int n4 = D_MODEL * D_MODEL / 4;
  int stride = gridDim.x * blockDim.x;
  for (int i = blockIdx.x * blockDim.x + threadIdx.x; i < n4; i += stride) {
    float4 v = reinterpret_cast<const float4*>(s)[i];
    reinterpret_cast<uint2*>(d)[i] = make_uint2(pack2(v.x, v.y), pack2(v.z, v.w));
  }
}

// ---------------- fused QKV projection GEMM ----------------
// grid (24, 64). T1 XCD-grouping remap (FETCH = compulsory).
// A (fp32) staged via global_load_lds with SOURCE-side XOR chunk swizzle
// (T21/m173): LDS slot s of row r holds global chunk s ^ (r&7), so fragment
// reads (slot = chunk ^ (row&7)) spread 16 lanes over 8 slots = 2-way = free.
// fp32->bf16 cvt happens on the consume side. B (bf16) staged linear (m97).
__global__ __launch_bounds__(256) void qkv_gemm(
    const float* __restrict__ qa, const float* __restrict__ ka, const float* __restrict__ va,
    const short* __restrict__ Wqkv,
    const float* __restrict__ bq, const float* __restrict__ bk, const float* __restrict__ bv,
    short* __restrict__ Qb, short* __restrict__ Kb, short* __restrict__ Vb)
{
  const int tid  = threadIdx.x;
  const int lane = tid & 63;
  const int wave = tid >> 6;
  // bijective remap: linear L -> (xcd = L&7, slot = L>>3); by ≡ xcd (mod 8)
  const int Lb  = blockIdx.x + 24 * blockIdx.y;
  const int xcd = Lb & 7;
  const int sl  = Lb >> 3;              // 0..191
  const int bx  = sl % 24;
  const int by  = (sl / 24) * 8 + xcd;  // 0..63

  const int sel = bx >> 3;
  const float* A    = (sel == 0) ? qa : (sel == 1) ? ka : va;
  const float* bias = (sel == 0) ? bq : (sel == 1) ? bk : bv;
  short* Out        = (sel == 0) ? Qb : (sel == 1) ? Kb : Vb;
  const int m0  = by * 128;
  const int n0g = bx * 128;          // row into Wqkv (0..3071)
  const int n0  = n0g & 1023;        // col into output tensor
  const int wm = (wave >> 1) * 64;
  const int wn = (wave & 1) * 64;

  __shared__ float Asf[128 * 32];    // fp32 A tile, source-swizzled (16 KB)
  __shared__ short Bs[128 * 32];     // bf16 B tile, linear (8 KB)

  f32x4 acc[4][4];
#pragma unroll
  for (int m = 0; m < 4; ++m)
#pragma unroll
    for (int n = 0; n < 4; ++n)
      acc[m][n] = (f32x4){0.f, 0.f, 0.f, 0.f};

  const int relrow = lane >> 3;                  // 0..7 within 8-row DMA group
  const int achunk = (lane & 7) ^ relrow;        // source chunk (XOR swizzle)
  const int qi = lane & 15, g = lane >> 4;
  const int r7 = qi & 7;                         // row&7 for all frag rows
  const int sA0 = (2 * g) ^ r7;                  // slot of chunk 2g
  const int sA1 = sA0 ^ 1;                       // slot of chunk 2g+1

  for (int k0 = 0; k0 < D_MODEL; k0 += 32) {
    // A: 4 DMA issues/wave (each 8 rows x 128B); source chunk-swizzled
#pragma unroll
    for (int i = 0; i < 4; ++i) {
      int r0 = (i * 4 + wave) * 8;
      gload16(&A[(size_t)(m0 + r0 + relrow) * D_MODEL + k0 + achunk * 4],
              &Asf[r0 * 32]);
    }
    // B: 2 DMA issues/wave, linear
#pragma unroll
    for (int i = 0; i < 2; ++i) {
      int t = i * 256 + wave * 64 + lane;
      int row = t >> 2, c8 = (t & 3) * 8;
      gload16(&Wqkv[(size_t)(n0g + row) * D_MODEL + k0 + c8],
              &Bs[i * 2048 + wave * 512]);
    }
    __syncthreads();

    short8 afr[4], bfr[4];
#pragma unroll
    for (int m = 0; m < 4; ++m) {
      const float* base = &Asf[(wm + m * 16 + qi) * 32];
      float4 fa = *reinterpret_cast<const float4*>(base + sA0 * 4);
      float4 fb = *reinterpret_cast<const float4*>(base + sA1 * 4);
      afr[m] = mk_frag(pack2(fa.x, fa.y), pack2(fa.z, fa.w),
                       pack2(fb.x, fb.y), pack2(fb.z, fb.w));
    }
#pragma unroll
    for (int n = 0; n < 4; ++n)
      bfr[n] = *reinterpret_cast<const short8*>(&Bs[(wn + n * 16 + qi) * 32 + g * 8]);
    __builtin_amdgcn_s_setprio(1);
#pragma unroll
    for (int m = 0; m < 4; ++m)
#pragma unroll
      for (int n = 0; n < 4; ++n)
        acc[m][n] = __builtin_amdgcn_mfma_f32_16x16x32_bf16(afr[m], bfr[n], acc[m][n], 0, 0, 0);
    __builtin_amdgcn_s_setprio(0);
    __syncthreads();
  }

#pragma unroll
  for (int n = 0; n < 4; ++n) {
    int col = n0 + wn + n * 16 + qi;
    float bval = bias[col];
#pragma unroll
    for (int m = 0; m < 4; ++m) {
      int rowb = m0 + wm + m * 16 + g * 4;
#pragma unroll
      for (int r = 0; r < 4; ++r)
        Out[(size_t)(rowb + r) * D_MODEL + col] = bf16_of(acc[m][n][r] + bval);
    }
  }
}

// ---------------- output GEMM: Out[M,N] = A[M,K] @ Bw[N,K]^T + bias (bf16 A, f32 out) ----------------
// Both operands via global_load_lds DMA; XCD-grouping remap like qkv_gemm.
__global__ __launch_bounds__(256) void gemm_out(
    const short* __restrict__ A, const short* __restrict__ Bw,
    const float* __restrict__ bias, float* __restrict__ Out,
    int M, int N, int K)
{
  const int tid  = threadIdx.x;
  const int lane = tid & 63;
  const int wave = tid >> 6;
  const int Lb  = blockIdx.x + 8 * blockIdx.y;
  const int xcd = Lb & 7;
  const int sl  = Lb >> 3;             // 0..63
  const int bx  = sl & 7;
  const int by  = (sl >> 3) * 8 + xcd; // 0..63
  const int m0 = by * 128;
  const int n0 = bx * 128;
  const int wm = (wave >> 1) * 64;
  const int wn = (wave & 1) * 64;

  __shared__ short As[128 * 32];
  __shared__ short Bs[128 * 32];

  f32x4 acc[4][4];
#pragma unroll
  for (int m = 0; m < 4; ++m)
#pragma unroll
    for (int n = 0; n < 4; ++n)
      acc[m][n] = (f32x4){0.f, 0.f, 0.f, 0.f};

  for (int k0 = 0; k0 < K; k0 += 32) {
#pragma unroll
    for (int i = 0; i < 2; ++i) {
      int t = i * 256 + wave * 64 + lane;
      int row = t >> 2, c8 = (t & 3) * 8;
      gload16(&A[(size_t)(m0 + row) * K + k0 + c8],  &As[i * 2048 + wave * 512]);
      gload16(&Bw[(size_t)(n0 + row) * K + k0 + c8], &Bs[i * 2048 + wave * 512]);
    }
    __syncthreads();

    short8 afr[4], bfr[4];
#pragma unroll
    for (int m = 0; m < 4; ++m)
      afr[m] = *reinterpret_cast<const short8*>(&As[(wm + m * 16 + (lane & 15)) * 32 + (lane >> 4) * 8]);
#pragma unroll
    for (int n = 0; n < 4; ++n)
      bfr[n] = *reinterpret_cast<const short8*>(&Bs[(wn + n * 16 + (lane & 15)) * 32 + (lane >> 4) * 8]);
#pragma unroll
    for (int m = 0; m < 4; ++m)
#pragma unroll
      for (int n = 0; n < 4; ++n)
        acc[m][n] = __builtin_amdgcn_mfma_f32_16x16x32_bf16(afr[m], bfr[n], acc[m][n], 0, 0, 0);
    __syncthreads();
  }

#pragma unroll
  for (int n = 0; n < 4; ++n) {
    int col = n0 + wn + n * 16 + (lane & 15);
    float bval = bias[col];
#pragma unroll
    for (int m = 0; m < 4; ++m) {
      int rowb = m0 + wm + m * 16 + (lane >> 4) * 4;
#pragma unroll
      for (int r = 0; r < 4; ++r)
        Out[(size_t)(rowb + r) * N + col] = acc[m][n][r] + bval;
    }
  }
}

// ---------------- per-head V transpose: V[B,S,D] -> VT[B,H,HDIM,SEQ] ----------------
__global__ __launch_bounds__(256) void transpose_v(const short* __restrict__ V,
                                                   short* __restrict__ VT) {
  int st = blockIdx.x;
  int bh = blockIdx.y;
  int b = bh >> 4, h = bh & 15;
  __shared__ short T[64][72];
  int tid = threadIdx.x;
#pragma unroll
  for (int i = 0; i < 2; ++i) {
    int c = tid + i * 256;
    int srow = c >> 3;
    int d8 = (c & 7) * 8;
    *reinterpret_cast<uint4*>(&T[srow][d8]) = *reinterpret_cast<const uint4*>(
        &V[((size_t)b * SEQ + st * 64 + srow) * D_MODEL + h * HDIM + d8]);
  }
  __syncthreads();
#pragma unroll
  for (int i = 0; i < 2; ++i) {
    int c = tid + i * 256;
    int drow = c >> 3;
    int s8 = (c & 7) * 8;
    __align__(16) short tmp[8];
#pragma unroll
    for (int j = 0; j < 8; ++j) tmp[j] = T[s8 + j][drow];
    *reinterpret_cast<uint4*>(
        &VT[(((size_t)b * NHEADS + h) * HDIM + drow) * SEQ + st * 64 + s8]) =
        *reinterpret_cast<uint4*>(tmp);
  }
}

// ---------------- flash attention, swapped-QK^T, fixed-shift softmax ----------------
// grid: (SEQ/128, B*H), 512 thr = 8 waves; each wave owns 16 query rows.
// Lane holds S^T[key][q], q=lane&15. Fixed softmax shift (10 nats) removes all
// max tracking; denominator accumulated via ones-MFMA (o_l). P lane-local for
// PV via key-permutation pi; V^T staged permuted.
__global__ __launch_bounds__(512) void attn_fwd(
    const short* __restrict__ Q,   // [B,S,D] bf16
    const short* __restrict__ Kg,  // [B,S,D] bf16
    const short* __restrict__ VT,  // [B,H,HDIM,SEQ] bf16
    short* __restrict__ Oc)        // [B,S,D] bf16 (concat)
{
  const int tid = threadIdx.x, lane = tid & 63, wave = tid >> 6;
  const int qi = lane & 15, g = lane >> 4;
  const int q0 = blockIdx.x * 128;
  const int bh = blockIdx.y, b = bh >> 4, h = bh & 15;

  __shared__ short Ks[2][64][72];   // [buf][key][d]
  __shared__ short Vs[2][64][72];   // [buf][d][pi(key)]

  const float CEXP = 0.18033688f;   // log2(e)/8
  const float SMC  = 14.4269504f;   // 80 * CEXP  (fixed 10-nat shift)
  const short8 ones = mk_frag(0x3F803F80u, 0x3F803F80u, 0x3F803F80u, 0x3F803F80u);

  short8 qfr[2];
  {
    int qrow = q0 + wave * 16 + qi;
    const short* qp = &Q[((size_t)b * SEQ + qrow) * D_MODEL + h * HDIM + g * 8];
    qfr[0] = *reinterpret_cast<const short8*>(qp);
    qfr[1] = *reinterpret_cast<const short8*>(qp + 32);
  }

  const size_t kbase = ((size_t)b * SEQ) * D_MODEL + h * HDIM;
  const size_t vbase = ((size_t)bh * HDIM) * SEQ;

  f32x4 o[4], o_l;
#pragma unroll
  for (int db = 0; db < 4; ++db) o[db] = (f32x4){0.f, 0.f, 0.f, 0.f};
  o_l = (f32x4){0.f, 0.f, 0.f, 0.f};

  // prologue: stage tile 0 into buffer 0 (1 K-chunk + 1 V-chunk per thread)
  {
    int row = tid >> 3, sub = tid & 7;
    *reinterpret_cast<uint4*>(&Ks[0][row][sub * 8]) =
        *reinterpret_cast<const uint4*>(&Kg[kbase + (size_t)row * D_MODEL + sub * 8]);
    uint4 vv = *reinterpret_cast<const uint4*>(&VT[vbase + (size_t)row * SEQ + sub * 8]);
    int posA = 32 * (sub >> 2) + 16 * (sub & 1) + 4 * ((sub >> 1) & 1);
    *reinterpret_cast<uint2*>(&Vs[0][row][posA])     = make_uint2(vv.x, vv.y);
    *reinterpret_cast<uint2*>(&Vs[0][row][posA + 8]) = make_uint2(vv.z, vv.w);
  }
  __syncthreads();

  for (int t = 0; t < SEQ / 64; ++t) {
    const int cur = t & 1;
    const bool more = (t + 1) < SEQ / 64;
    const int row = tid >> 3, sub = tid & 7;
    uint4 kreg, vreg;
    if (more) {
      int k0 = (t + 1) * 64;
      kreg = *reinterpret_cast<const uint4*>(&Kg[kbase + (size_t)(k0 + row) * D_MODEL + sub * 8]);
      vreg = *reinterpret_cast<const uint4*>(&VT[vbase + (size_t)row * SEQ + k0 + sub * 8]);
    }

    // QK^T swapped: A=K (row=key), B=Q (col=q)
    f32x4 st[4];
    __builtin_amdgcn_s_setprio(1);
#pragma unroll
    for (int n = 0; n < 4; ++n) {
      short8 a0 = *reinterpret_cast<const short8*>(&Ks[cur][n * 16 + qi][g * 8]);
      short8 a1 = *reinterpret_cast<const short8*>(&Ks[cur][n * 16 + qi][32 + g * 8]);
      f32x4 z = (f32x4){0.f, 0.f, 0.f, 0.f};
      z = __builtin_amdgcn_mfma_f32_16x16x32_bf16(a0, qfr[0], z, 0, 0, 0);
      z = __builtin_amdgcn_mfma_f32_16x16x32_bf16(a1, qfr[1], z, 0, 0, 0);
      st[n] = z;
    }
    __builtin_amdgcn_s_setprio(0);

    // fixed-shift softmax: p = 2^(s*CEXP - SMC); no max, no cross-lane
    unsigned pk[4][2];
#pragma unroll
    for (int n = 0; n < 4; ++n) {
#pragma unroll
      for (int r = 0; r < 4; ++r)
        st[n][r] = fast_exp2(fmaf(st[n][r], CEXP, -SMC));
      pk[n][0] = pack2(st[n][0], st[n][1]);
      pk[n][1] = pack2(st[n][2], st[n][3]);
    }

    // stage next tile into the other buffer (loads already in flight)
    if (more) {
      const int nb = cur ^ 1;
      *reinterpret_cast<uint4*>(&Ks[nb][row][sub * 8]) = kreg;
      int posA = 32 * (sub >> 2) + 16 * (sub & 1) + 4 * ((sub >> 1) & 1);
      *reinterpret_cast<uint2*>(&Vs[nb][row][posA])     = make_uint2(vreg.x, vreg.y);
      *reinterpret_cast<uint2*>(&Vs[nb][row][posA + 8]) = make_uint2(vreg.z, vreg.w);
    }

    // PV: O^T[d][q] += V^T[d][pi(k)] * P^T[pi(k)][q]; l via ones-MFMA
    short8 pb0 = mk_frag(pk[0][0], pk[0][1], pk[1][0], pk[1][1]);
    short8 pb1 = mk_frag(pk[2][0], pk[2][1], pk[3][0], pk[3][1]);
    __builtin_amdgcn_s_setprio(1);
#pragma unroll
    for (int db = 0; db < 4; ++db) {
      short8 va0 = *reinterpret_cast<const short8*>(&Vs[cur][db * 16 + qi][g * 8]);
      short8 va1 = *reinterpret_cast<const short8*>(&Vs[cur][db * 16 + qi][32 + g * 8]);
      o[db] = __builtin_amdgcn_mfma_f32_16x16x32_bf16(va0, pb0, o[db], 0, 0, 0);
      o[db] = __builtin_amdgcn_mfma_f32_16x16x32_bf16(va1, pb1, o[db], 0, 0, 0);
    }
    o_l = __builtin_amdgcn_mfma_f32_16x16x32_bf16(ones, pb0, o_l, 0, 0, 0);
    o_l = __builtin_amdgcn_mfma_f32_16x16x32_bf16(ones, pb1, o_l, 0, 0, 0);
    __builtin_amdgcn_s_setprio(0);

    __syncthreads();
  }

  // epilogue: transpose O^T -> rows via dead K buffer, then coalesced store
  short (*Os)[72] = reinterpret_cast<short(*)[72]>(&Ks[0][0][0]);  // [128][72]
  float inv = 1.f / o_l[0];
#pragma unroll
  for (int db = 0; db < 4; ++db)
#pragma unroll
    for (int r = 0; r < 4; ++r)
      Os[wave * 16 + qi][db * 16 + g * 4 + r] = bf16_of(o[db][r] * inv);
  __syncthreads();
#pragma unroll
  for (int i = 0; i < 2; ++i) {
    int c = tid + i * 512;
    int row = c >> 3, sub = c & 7;
    *reinterpret_cast<uint4*>(&Oc[((size_t)b * SEQ + q0 + row) * D_MODEL + h * HDIM + sub * 8]) =
        *reinterpret_cast<const uint4*>(&Os[row][sub * 8]);
  }
}

// ---------------- launch ----------------
extern "C" void kernel_launch(void* const* d_in, const int* in_sizes, int n_in,
                              void* d_out, int out_size, void* d_ws, size_t ws_size,
                              hipStream_t stream)
{
  const float* q  = (const float*)d_in[0];
  const float* k  = (const float*)d_in[1];
  const float* v  = (const float*)d_in[2];
  const float* Wq = (const float*)d_in[3];
  const float* bq = (const float*)d_in[4];
  const float* Wk = (const float*)d_in[5];
  const float* bk = (const float*)d_in[6];
  const float* Wv = (const float*)d_in[7];
  const float* bv = (const float*)d_in[8];
  const float* Wo = (const float*)d_in[9];
  const float* bo = (const float*)d_in[10];

  char* ws = (char*)d_ws;
  const size_t MB = 1ull << 20;
  short* Wqkv_b = (short*)(ws + 0 * MB);   // [3072][1024] bf16 (q,k,v contiguous)
  short* Wo_b   = (short*)(ws + 6 * MB);
  short* Qb     = (short*)(ws + 8 * MB);
  short* Kb     = (short*)(ws + 24 * MB);
  short* Vb     = (short*)(ws + 40 * MB);
  short* VTb    = (short*)(ws + 56 * MB);
  short* Ac     = (short*)(ws + 40 * MB);  // aliases Vb (dead after transpose)

  const int M = BATCH * SEQ;

  cvt4<<<dim3(256, 4), 256, 0, stream>>>(Wq, Wk, Wv, Wo, Wqkv_b);

  qkv_gemm<<<dim3(24, M / 128), 256, 0, stream>>>(q, k, v, Wqkv_b, bq, bk, bv, Qb, Kb, Vb);

  transpose_v<<<dim3(SEQ / 64, BATCH * NHEADS), 256, 0, stream>>>(Vb, VTb);

  attn_fwd<<<dim3(SEQ / 128, BATCH * NHEADS), 512, 0, stream>>>(Qb, Kb, VTb, Ac);

  gemm_out<<<dim3(D_MODEL / 128, M / 128), 256, 0, stream>>>(Ac, Wo_b, bo, (float*)d_out,
                                                             M, D_MODEL, D_MODEL);
}

// Round 9
// 219.400 us; speedup vs baseline: 1.3011x; 1.0079x over previous
//
#include <hip/hip_runtime.h>
#include <hip/hip_bf16.h>
#include <math.h>

#define D_MODEL 1024
#define NHEADS  16
#define HDIM    64
#define BATCH   4
#define SEQ     2048

typedef __attribute__((ext_vector_type(8))) short short8;
typedef __attribute__((ext_vector_type(4))) float f32x4;

__device__ __forceinline__ short bf16_of(float f) {
  __hip_bfloat16 h = __float2bfloat16(f);
  return *reinterpret_cast<short*>(&h);
}

__device__ __forceinline__ unsigned pack2(float lo, float hi) {
  return (unsigned)(unsigned short)bf16_of(lo) |
         ((unsigned)(unsigned short)bf16_of(hi) << 16);
}

__device__ __forceinline__ short8 mk_frag(unsigned a, unsigned b, unsigned c, unsigned d) {
  union { unsigned u[4]; short8 s; } t;
  t.u[0] = a; t.u[1] = b; t.u[2] = c; t.u[3] = d;
  return t.s;
}

__device__ __forceinline__ float fast_exp2(float x) {
  float r;
  asm("v_exp_f32 %0, %1" : "=v"(r) : "v"(x));
  return r;
}

// async global->LDS DMA, 16B per lane; lds dest = wave-uniform base + lane*16
__device__ __forceinline__ void gload16(const void* g, void* l) {
  __builtin_amdgcn_global_load_lds((const __attribute__((address_space(1))) void*)g,
                                   (__attribute__((address_space(3))) void*)l, 16, 0, 0);
}

// ---------------- fp32 -> bf16 convert: 4 weights + q,k,v inputs, one launch ----------------
__global__ __launch_bounds__(256) void cvt7(
    const float* __restrict__ Wq, const float* __restrict__ Wk,
    const float* __restrict__ Wv, const float* __restrict__ Wo,
    const float* __restrict__ q,  const float* __restrict__ k,
    const float* __restrict__ v,
    short* __restrict__ wdst, short* __restrict__ qc,
    short* __restrict__ kc,   short* __restrict__ vc)
{
  const int w = blockIdx.y;
  const float* s;
  short* d;
  int n4;
  if (w < 4) {
    s = (w == 0) ? Wq : (w == 1) ? Wk : (w == 2) ? Wv : Wo;
    d = wdst + (size_t)w * D_MODEL * D_MODEL;
    n4 = D_MODEL * D_MODEL / 4;
  } else {
    s = (w == 4) ? q : (w == 5) ? k : v;
    d = (w == 4) ? qc : (w == 5) ? kc : vc;
    n4 = BATCH * SEQ * D_MODEL / 4;
  }
  int stride = gridDim.x * blockDim.x;
  for (int i = blockIdx.x * blockDim.x + threadIdx.x; i < n4; i += stride) {
    float4 fv = reinterpret_cast<const float4*>(s)[i];
    reinterpret_cast<uint2*>(d)[i] = make_uint2(pack2(fv.x, fv.y), pack2(fv.z, fv.w));
  }
}

// ---------------- fused QKV projection GEMM (pure bf16, gemm_out structure) ----------------
// grid (24, 64). T1 XCD-grouping remap; bx>>3 selects {q,k,v}.
// Both operands via global_load_lds DMA into linear LDS (m97 structure).
__global__ __launch_bounds__(256) void qkv_gemm(
    const short* __restrict__ qc, const short* __restrict__ kc, const short* __restrict__ vc,
    const short* __restrict__ Wqkv,
    const float* __restrict__ bq, const float* __restrict__ bk, const float* __restrict__ bv,
    short* __restrict__ Qb, short* __restrict__ Kb, short* __restrict__ Vb)
{
  const int tid  = threadIdx.x;
  const int lane = tid & 63;
  const int wave = tid >> 6;
  // bijective remap: linear L -> (xcd = L&7, slot = L>>3); by ≡ xcd (mod 8)
  const int Lb  = blockIdx.x + 24 * blockIdx.y;
  const int xcd = Lb & 7;
  const int sl  = Lb >> 3;              // 0..191
  const int bx  = sl % 24;
  const int by  = (sl / 24) * 8 + xcd;  // 0..63

  const int sel = bx >> 3;
  const short* A    = (sel == 0) ? qc : (sel == 1) ? kc : vc;
  const float* bias = (sel == 0) ? bq : (sel == 1) ? bk : bv;
  short* Out        = (sel == 0) ? Qb : (sel == 1) ? Kb : Vb;
  const int m0  = by * 128;
  const int n0g = bx * 128;          // row into Wqkv (0..3071)
  const int n0  = n0g & 1023;        // col into output tensor
  const int wm = (wave >> 1) * 64;
  const int wn = (wave & 1) * 64;

  __shared__ short As[128 * 32];
  __shared__ short Bs[128 * 32];

  f32x4 acc[4][4];
#pragma unroll
  for (int m = 0; m < 4; ++m)
#pragma unroll
    for (int n = 0; n < 4; ++n)
      acc[m][n] = (f32x4){0.f, 0.f, 0.f, 0.f};

  for (int k0 = 0; k0 < D_MODEL; k0 += 32) {
#pragma unroll
    for (int i = 0; i < 2; ++i) {
      int t = i * 256 + wave * 64 + lane;
      int row = t >> 2, c8 = (t & 3) * 8;
      gload16(&A[(size_t)(m0 + row) * D_MODEL + k0 + c8],    &As[i * 2048 + wave * 512]);
      gload16(&Wqkv[(size_t)(n0g + row) * D_MODEL + k0 + c8], &Bs[i * 2048 + wave * 512]);
    }
    __syncthreads();

    short8 afr[4], bfr[4];
#pragma unroll
    for (int m = 0; m < 4; ++m)
      afr[m] = *reinterpret_cast<const short8*>(&As[(wm + m * 16 + (lane & 15)) * 32 + (lane >> 4) * 8]);
#pragma unroll
    for (int n = 0; n < 4; ++n)
      bfr[n] = *reinterpret_cast<const short8*>(&Bs[(wn + n * 16 + (lane & 15)) * 32 + (lane >> 4) * 8]);
#pragma unroll
    for (int m = 0; m < 4; ++m)
#pragma unroll
      for (int n = 0; n < 4; ++n)
        acc[m][n] = __builtin_amdgcn_mfma_f32_16x16x32_bf16(afr[m], bfr[n], acc[m][n], 0, 0, 0);
    __syncthreads();
  }

#pragma unroll
  for (int n = 0; n < 4; ++n) {
    int col = n0 + wn + n * 16 + (lane & 15);
    float bval = bias[col];
#pragma unroll
    for (int m = 0; m < 4; ++m) {
      int rowb = m0 + wm + m * 16 + (lane >> 4) * 4;
#pragma unroll
      for (int r = 0; r < 4; ++r)
        Out[(size_t)(rowb + r) * D_MODEL + col] = bf16_of(acc[m][n][r] + bval);
    }
  }
}

// ---------------- output GEMM: Out[M,N] = A[M,K] @ Bw[N,K]^T + bias (bf16 A, f32 out) ----------------
// Both operands via global_load_lds DMA; XCD-grouping remap like qkv_gemm.
__global__ __launch_bounds__(256) void gemm_out(
    const short* __restrict__ A, const short* __restrict__ Bw,
    const float* __restrict__ bias, float* __restrict__ Out,
    int M, int N, int K)
{
  const int tid  = threadIdx.x;
  const int lane = tid & 63;
  const int wave = tid >> 6;
  const int Lb  = blockIdx.x + 8 * blockIdx.y;
  const int xcd = Lb & 7;
  const int sl  = Lb >> 3;             // 0..63
  const int bx  = sl & 7;
  const int by  = (sl >> 3) * 8 + xcd; // 0..63
  const int m0 = by * 128;
  const int n0 = bx * 128;
  const int wm = (wave >> 1) * 64;
  const int wn = (wave & 1) * 64;

  __shared__ short As[128 * 32];
  __shared__ short Bs[128 * 32];

  f32x4 acc[4][4];
#pragma unroll
  for (int m = 0; m < 4; ++m)
#pragma unroll
    for (int n = 0; n < 4; ++n)
      acc[m][n] = (f32x4){0.f, 0.f, 0.f, 0.f};

  for (int k0 = 0; k0 < K; k0 += 32) {
#pragma unroll
    for (int i = 0; i < 2; ++i) {
      int t = i * 256 + wave * 64 + lane;
      int row = t >> 2, c8 = (t & 3) * 8;
      gload16(&A[(size_t)(m0 + row) * K + k0 + c8],  &As[i * 2048 + wave * 512]);
      gload16(&Bw[(size_t)(n0 + row) * K + k0 + c8], &Bs[i * 2048 + wave * 512]);
    }
    __syncthreads();

    short8 afr[4], bfr[4];
#pragma unroll
    for (int m = 0; m < 4; ++m)
      afr[m] = *reinterpret_cast<const short8*>(&As[(wm + m * 16 + (lane & 15)) * 32 + (lane >> 4) * 8]);
#pragma unroll
    for (int n = 0; n < 4; ++n)
      bfr[n] = *reinterpret_cast<const short8*>(&Bs[(wn + n * 16 + (lane & 15)) * 32 + (lane >> 4) * 8]);
#pragma unroll
    for (int m = 0; m < 4; ++m)
#pragma unroll
      for (int n = 0; n < 4; ++n)
        acc[m][n] = __builtin_amdgcn_mfma_f32_16x16x32_bf16(afr[m], bfr[n], acc[m][n], 0, 0, 0);
    __syncthreads();
  }

#pragma unroll
  for (int n = 0; n < 4; ++n) {
    int col = n0 + wn + n * 16 + (lane & 15);
    float bval = bias[col];
#pragma unroll
    for (int m = 0; m < 4; ++m) {
      int rowb = m0 + wm + m * 16 + (lane >> 4) * 4;
#pragma unroll
      for (int r = 0; r < 4; ++r)
        Out[(size_t)(rowb + r) * N + col] = acc[m][n][r] + bval;
    }
  }
}

// ---------------- per-head V transpose: V[B,S,D] -> VT[B,H,HDIM,SEQ] ----------------
__global__ __launch_bounds__(256) void transpose_v(const short* __restrict__ V,
                                                   short* __restrict__ VT) {
  int st = blockIdx.x;
  int bh = blockIdx.y;
  int b = bh >> 4, h = bh & 15;
  __shared__ short T[64][72];
  int tid = threadIdx.x;
#pragma unroll
  for (int i = 0; i < 2; ++i) {
    int c = tid + i * 256;
    int srow = c >> 3;
    int d8 = (c & 7) * 8;
    *reinterpret_cast<uint4*>(&T[srow][d8]) = *reinterpret_cast<const uint4*>(
        &V[((size_t)b * SEQ + st * 64 + srow) * D_MODEL + h * HDIM + d8]);
  }
  __syncthreads();
#pragma unroll
  for (int i = 0; i < 2; ++i) {
    int c = tid + i * 256;
    int drow = c >> 3;
    int s8 = (c & 7) * 8;
    __align__(16) short tmp[8];
#pragma unroll
    for (int j = 0; j < 8; ++j) tmp[j] = T[s8 + j][drow];
    *reinterpret_cast<uint4*>(
        &VT[(((size_t)b * NHEADS + h) * HDIM + drow) * SEQ + st * 64 + s8]) =
        *reinterpret_cast<uint4*>(tmp);
  }
}

// ---------------- flash attention, swapped-QK^T, fixed-shift softmax ----------------
// grid: (SEQ/128, B*H), 512 thr = 8 waves; each wave owns 16 query rows.
// Lane holds S^T[key][q], q=lane&15. Fixed softmax shift (10 nats) removes all
// max tracking; denominator accumulated via ones-MFMA (o_l). P lane-local for
// PV via key-permutation pi; V^T staged permuted.
__global__ __launch_bounds__(512) void attn_fwd(
    const short* __restrict__ Q,   // [B,S,D] bf16
    const short* __restrict__ Kg,  // [B,S,D] bf16
    const short* __restrict__ VT,  // [B,H,HDIM,SEQ] bf16
    short* __restrict__ Oc)        // [B,S,D] bf16 (concat)
{
  const int tid = threadIdx.x, lane = tid & 63, wave = tid >> 6;
  const int qi = lane & 15, g = lane >> 4;
  const int q0 = blockIdx.x * 128;
  const int bh = blockIdx.y, b = bh >> 4, h = bh & 15;

  __shared__ short Ks[2][64][72];   // [buf][key][d]
  __shared__ short Vs[2][64][72];   // [buf][d][pi(key)]

  const float CEXP = 0.18033688f;   // log2(e)/8
  const float SMC  = 14.4269504f;   // 80 * CEXP  (fixed 10-nat shift)
  const short8 ones = mk_frag(0x3F803F80u, 0x3F803F80u, 0x3F803F80u, 0x3F803F80u);

  short8 qfr[2];
  {
    int qrow = q0 + wave * 16 + qi;
    const short* qp = &Q[((size_t)b * SEQ + qrow) * D_MODEL + h * HDIM + g * 8];
    qfr[0] = *reinterpret_cast<const short8*>(qp);
    qfr[1] = *reinterpret_cast<const short8*>(qp + 32);
  }

  const size_t kbase = ((size_t)b * SEQ) * D_MODEL + h * HDIM;
  const size_t vbase = ((size_t)bh * HDIM) * SEQ;

  f32x4 o[4], o_l;
#pragma unroll
  for (int db = 0; db < 4; ++db) o[db] = (f32x4){0.f, 0.f, 0.f, 0.f};
  o_l = (f32x4){0.f, 0.f, 0.f, 0.f};

  // prologue: stage tile 0 into buffer 0 (1 K-chunk + 1 V-chunk per thread)
  {
    int row = tid >> 3, sub = tid & 7;
    *reinterpret_cast<uint4*>(&Ks[0][row][sub * 8]) =
        *reinterpret_cast<const uint4*>(&Kg[kbase + (size_t)row * D_MODEL + sub * 8]);
    uint4 vv = *reinterpret_cast<const uint4*>(&VT[vbase + (size_t)row * SEQ + sub * 8]);
    int posA = 32 * (sub >> 2) + 16 * (sub & 1) + 4 * ((sub >> 1) & 1);
    *reinterpret_cast<uint2*>(&Vs[0][row][posA])     = make_uint2(vv.x, vv.y);
    *reinterpret_cast<uint2*>(&Vs[0][row][posA + 8]) = make_uint2(vv.z, vv.w);
  }
  __syncthreads();

  for (int t = 0; t < SEQ / 64; ++t) {
    const int cur = t & 1;
    const bool more = (t + 1) < SEQ / 64;
    const int row = tid >> 3, sub = tid & 7;
    uint4 kreg, vreg;
    if (more) {
      int k0 = (t + 1) * 64;
      kreg = *reinterpret_cast<const uint4*>(&Kg[kbase + (size_t)(k0 + row) * D_MODEL + sub * 8]);
      vreg = *reinterpret_cast<const uint4*>(&VT[vbase + (size_t)row * SEQ + k0 + sub * 8]);
    }

    // QK^T swapped: A=K (row=key), B=Q (col=q)
    f32x4 st[4];
    __builtin_amdgcn_s_setprio(1);
#pragma unroll
    for (int n = 0; n < 4; ++n) {
      short8 a0 = *reinterpret_cast<const short8*>(&Ks[cur][n * 16 + qi][g * 8]);
      short8 a1 = *reinterpret_cast<const short8*>(&Ks[cur][n * 16 + qi][32 + g * 8]);
      f32x4 z = (f32x4){0.f, 0.f, 0.f, 0.f};
      z = __builtin_amdgcn_mfma_f32_16x16x32_bf16(a0, qfr[0], z, 0, 0, 0);
      z = __builtin_amdgcn_mfma_f32_16x16x32_bf16(a1, qfr[1], z, 0, 0, 0);
      st[n] = z;
    }
    __builtin_amdgcn_s_setprio(0);

    // fixed-shift softmax: p = 2^(s*CEXP - SMC); no max, no cross-lane
    unsigned pk[4][2];
#pragma unroll
    for (int n = 0; n < 4; ++n) {
#pragma unroll
      for (int r = 0; r < 4; ++r)
        st[n][r] = fast_exp2(fmaf(st[n][r], CEXP, -SMC));
      pk[n][0] = pack2(st[n][0], st[n][1]);
      pk[n][1] = pack2(st[n][2], st[n][3]);
    }

    // stage next tile into the other buffer (loads already in flight)
    if (more) {
      const int nb = cur ^ 1;
      *reinterpret_cast<uint4*>(&Ks[nb][row][sub * 8]) = kreg;
      int posA = 32 * (sub >> 2) + 16 * (sub & 1) + 4 * ((sub >> 1) & 1);
      *reinterpret_cast<uint2*>(&Vs[nb][row][posA])     = make_uint2(vreg.x, vreg.y);
      *reinterpret_cast<uint2*>(&Vs[nb][row][posA + 8]) = make_uint2(vreg.z, vreg.w);
    }

    // PV: O^T[d][q] += V^T[d][pi(k)] * P^T[pi(k)][q]; l via ones-MFMA
    short8 pb0 = mk_frag(pk[0][0], pk[0][1], pk[1][0], pk[1][1]);
    short8 pb1 = mk_frag(pk[2][0], pk[2][1], pk[3][0], pk[3][1]);
    __builtin_amdgcn_s_setprio(1);
#pragma unroll
    for (int db = 0; db < 4; ++db) {
      short8 va0 = *reinterpret_cast<const short8*>(&Vs[cur][db * 16 + qi][g * 8]);
      short8 va1 = *reinterpret_cast<const short8*>(&Vs[cur][db * 16 + qi][32 + g * 8]);
      o[db] = __builtin_amdgcn_mfma_f32_16x16x32_bf16(va0, pb0, o[db], 0, 0, 0);
      o[db] = __builtin_amdgcn_mfma_f32_16x16x32_bf16(va1, pb1, o[db], 0, 0, 0);
    }
    o_l = __builtin_amdgcn_mfma_f32_16x16x32_bf16(ones, pb0, o_l, 0, 0, 0);
    o_l = __builtin_amdgcn_mfma_f32_16x16x32_bf16(ones, pb1, o_l, 0, 0, 0);
    __builtin_amdgcn_s_setprio(0);

    __syncthreads();
  }

  // epilogue: transpose O^T -> rows via dead K buffer, then coalesced store
  short (*Os)[72] = reinterpret_cast<short(*)[72]>(&Ks[0][0][0]);  // [128][72]
  float inv = 1.f / o_l[0];
#pragma unroll
  for (int db = 0; db < 4; ++db)
#pragma unroll
    for (int r = 0; r < 4; ++r)
      Os[wave * 16 + qi][db * 16 + g * 4 + r] = bf16_of(o[db][r] * inv);
  __syncthreads();
#pragma unroll
  for (int i = 0; i < 2; ++i) {
    int c = tid + i * 512;
    int row = c >> 3, sub = c & 7;
    *reinterpret_cast<uint4*>(&Oc[((size_t)b * SEQ + q0 + row) * D_MODEL + h * HDIM + sub * 8]) =
        *reinterpret_cast<const uint4*>(&Os[row][sub * 8]);
  }
}

// ---------------- launch ----------------
extern "C" void kernel_launch(void* const* d_in, const int* in_sizes, int n_in,
                              void* d_out, int out_size, void* d_ws, size_t ws_size,
                              hipStream_t stream)
{
  const float* q  = (const float*)d_in[0];
  const float* k  = (const float*)d_in[1];
  const float* v  = (const float*)d_in[2];
  const float* Wq = (const float*)d_in[3];
  const float* bq = (const float*)d_in[4];
  const float* Wk = (const float*)d_in[5];
  const float* bk = (const float*)d_in[6];
  const float* Wv = (const float*)d_in[7];
  const float* bv = (const float*)d_in[8];
  const float* Wo = (const float*)d_in[9];
  const float* bo = (const float*)d_in[10];

  char* ws = (char*)d_ws;
  const size_t MB = 1ull << 20;
  short* Wqkv_b = (short*)(ws + 0 * MB);   // [3072][1024] bf16 (q,k,v contiguous)
  short* Wo_b   = (short*)(ws + 6 * MB);
  short* Qb     = (short*)(ws + 8 * MB);
  short* Kb     = (short*)(ws + 24 * MB);
  short* Vb     = (short*)(ws + 40 * MB);
  short* qc     = (short*)(ws + 56 * MB);  // bf16-converted inputs
  short* kc     = (short*)(ws + 72 * MB);
  short* vc     = (short*)(ws + 88 * MB);
  short* VTb    = (short*)(ws + 56 * MB);  // aliases qc (dead after qkv_gemm)
  short* Ac     = (short*)(ws + 40 * MB);  // aliases Vb (dead after transpose)

  const int M = BATCH * SEQ;

  cvt7<<<dim3(256, 7), 256, 0, stream>>>(Wq, Wk, Wv, Wo, q, k, v, Wqkv_b, qc, kc, vc);

  qkv_gemm<<<dim3(24, M / 128), 256, 0, stream>>>(qc, kc, vc, Wqkv_b, bq, bk, bv, Qb, Kb, Vb);

  transpose_v<<<dim3(SEQ / 64, BATCH * NHEADS), 256, 0, stream>>>(Vb, VTb);

  attn_fwd<<<dim3(SEQ / 128, BATCH * NHEADS), 512, 0, stream>>>(Qb, Kb, VTb, Ac);

  gemm_out<<<dim3(D_MODEL / 128, M / 128), 256, 0, stream>>>(Ac, Wo_b, bo, (float*)d_out,
                                                             M, D_MODEL, D_MODEL);
}